// Round 4
// baseline (308.559 us; speedup 1.0000x reference)
//
#include <hip/hip_runtime.h>

#define BB 8
#define NN 16384
#define CC 256
#define KK 4096
#define FDIM 258
#define FP 256          // GEMM K: real channels 0..255; 256/257 via rank-2 epilogue
#define OC 512
#define NPTS (BB * NN)  // 131072
#define NROWS (BB * KK) // 32768
#define CAP 64          // per-cluster list capacity (Poisson(4); max ~18)
#define LNEPS 1e-5f

// output layout (floats)
#define OUT_FEAT_OFF 65536
#define OUT_MASK_OFF (65536 + 16777216)

// workspace offsets (float units)
#define OFF_MAX 0
#define OFF_ICOUNT 16
#define MEMSET_FLOATS (16 + NROWS)            // only max + icount need zeroing
#define OFF_ACCH 32784                        // fp16 region, NROWS*FP halves
#define ACC_FSLOTS (NROWS * FP / 2)           // 4,194,304
#define OFF_INV (OFF_ACCH + ACC_FSLOTS)       // 4,227,088
#define OFF_LIST (OFF_INV + NROWS)            // 4,259,856 (ints)
#define OFF_WPH (OFF_LIST + NROWS * CAP)      // 6,357,008 (fp16, OC*FP halves)
#define OFF_RP (OFF_WPH + OC * FP / 2)        // 6,422,544 (2 fp32 per row)
#define OFF_WC (OFF_RP + NROWS * 2)           // 6,488,080 (wcol 2x512 fp32)

typedef _Float16 h8v __attribute__((ext_vector_type(8)));
typedef _Float16 h4v __attribute__((ext_vector_type(4)));
typedef float f4v __attribute__((ext_vector_type(4)));

// Fused prep: blocks [0,512) -> per-point max-reduce + cluster list build;
// blocks [512,640) -> lin_w cols 0..255 into fp16 Wh[OC][FP];
// block 640 -> lin_w cols 256/257 into fp32 wc[2][OC].
#define PREP_PB 512
#define PREP_WB 129

__global__ __launch_bounds__(256) void k_prep(const float* __restrict__ pos,
                                              const int* __restrict__ asg,
                                              const float* __restrict__ lw,
                                              float* ws) {
    int bid = blockIdx.x;
    if (bid < PREP_PB) {
        int i = bid * 256 + threadIdx.x;  // exactly covers NPTS
        int* icount = (int*)(ws + OFF_ICOUNT);
        int* list = (int*)(ws + OFF_LIST);
        float2 p = ((const float2*)pos)[i];
        int b = i >> 14;
        int row = b * KK + asg[i];
        int slot = atomicAdd(icount + row, 1);
        if (slot < CAP) list[row * CAP + slot] = i;
        float mx = p.x, my = p.y;
        for (int off = 32; off > 0; off >>= 1) {
            mx = fmaxf(mx, __shfl_down(mx, off));
            my = fmaxf(my, __shfl_down(my, off));
        }
        if ((threadIdx.x & 63) == 0) {
            atomicMax((int*)(ws + OFF_MAX + 0), __float_as_int(mx));
            atomicMax((int*)(ws + OFF_MAX + 1), __float_as_int(my));
        }
    } else if (bid < PREP_PB + 128) {
        _Float16* Wh = (_Float16*)(ws + OFF_WPH);
        int e = (bid - PREP_PB) * 1024 + threadIdx.x * 4;  // 4 halves/thread
        int o = e >> 8, f = e & 255;  // f <= 252 < FDIM: no pad conditional
        h4v h;
#pragma unroll
        for (int u = 0; u < 4; ++u) h[u] = (_Float16)lw[o * FDIM + f + u];
        *(h4v*)(Wh + e) = h;
    } else {
        int o = threadIdx.x;  // cols 256/257 of lw, fp32
        ws[OFF_WC + o] = lw[o * FDIM + 256];
        ws[OFF_WC + 512 + o] = lw[o * FDIM + 257];
        o += 256;
        ws[OFF_WC + o] = lw[o * FDIM + 256];
        ws[OFF_WC + 512 + o] = lw[o * FDIM + 257];
    }
}

// One wave per cluster row, QUARTER-wave per point: 4 points in flight per
// batch (4 independent 256B-coalesced loads), 4-step shfl_xor reduce within
// each 16-lane quarter for mean/var, single xor-16/32 merge at the end.
// LN'd rel-pos channels (256/257) go to rp[row][2] for the gemm epilogue.
__global__ __launch_bounds__(256) void k_gather(
    const float* __restrict__ feat, const float* __restrict__ pos,
    const float* __restrict__ nw, const float* __restrict__ nb,
    float* ws, float* __restrict__ out) {
    int t = threadIdx.x;
    int lane = t & 63;
    int bswz = ((blockIdx.x & 7) << 10) + (blockIdx.x >> 3);  // XCD-grouped rows
    int row = (bswz << 2) + (t >> 6);  // 4 waves/block
    int q = lane >> 4;   // quarter id = point slot within batch
    int ll = lane & 15;  // lane within quarter: channels q*64 + ll*4 + j
    const int* icount = (const int*)(ws + OFF_ICOUNT);
    const int* list = (const int*)(ws + OFF_LIST);
    _Float16* Ah = (_Float16*)(ws + OFF_ACCH);

    int cnt = icount[row];
    if (cnt > CAP) cnt = CAP;
    float fcnt = (float)cnt;
    float invc = 1.f / fmaxf(fcnt, 1.f);
    float mxx = ws[OFF_MAX + 0], mxy = ws[OFF_MAX + 1];

    int ptl = (lane < cnt) ? list[row * CAP + lane] : 0;
    float px = 0.f, py = 0.f;
    if (lane < cnt) {
        float2 p = ((const float2*)pos)[ptl];
        px = p.x / mxx;
        py = p.y / mxy;
    }
    float sx = px, sy = py;
    for (int m = 32; m; m >>= 1) {
        sx += __shfl_xor(sx, m);
        sy += __shfl_xor(sy, m);
    }
    float meanx = sx * invc, meany = sy * invc;
    float valid = (cnt > 0) ? 1.f : 0.f;
    if (lane == 0) {
        out[2 * row + 0] = meanx * valid;
        out[2 * row + 1] = meany * valid;
        out[OUT_MASK_OFF + row] = valid;
        ws[OFF_INV + row] = invc;
    }

    // acc a<u>: channels u*64 + ll*4 + j, partial over points s≡q (mod 4)
    float4 a0 = {0.f, 0.f, 0.f, 0.f}, a1 = {0.f, 0.f, 0.f, 0.f};
    float4 a2 = {0.f, 0.f, 0.f, 0.f}, a3 = {0.f, 0.f, 0.f, 0.f};
    float arx = 0.f, ary = 0.f;
    for (int s0 = 0; s0 < cnt; s0 += 4) {
        int s = s0 + q;  // this quarter's point (may be >= cnt on tail)
        int pt = __shfl(ptl, s);
        float rx = __shfl(px, s) - meanx;
        float ry = __shfl(py, s) - meany;
        const float4* fr = (const float4*)(feat + (size_t)pt * CC);
        float4 v0 = fr[ll];       // channels ll*4       .. +3
        float4 v1 = fr[16 + ll];  // channels 64+ll*4    .. +3
        float4 v2 = fr[32 + ll];  // channels 128+ll*4   .. +3
        float4 v3 = fr[48 + ll];  // channels 192+ll*4   .. +3
        float S = (v0.x + v0.y + v0.z + v0.w) + (v1.x + v1.y + v1.z + v1.w) +
                  (v2.x + v2.y + v2.z + v2.w) + (v3.x + v3.y + v3.z + v3.w);
        float Q = v0.x * v0.x + v0.y * v0.y + v0.z * v0.z + v0.w * v0.w +
                  v1.x * v1.x + v1.y * v1.y + v1.z * v1.z + v1.w * v1.w +
                  v2.x * v2.x + v2.y * v2.y + v2.z * v2.z + v2.w * v2.w +
                  v3.x * v3.x + v3.y * v3.y + v3.z * v3.z + v3.w * v3.w;
        for (int m = 1; m < 16; m <<= 1) {  // reduce within quarter
            S += __shfl_xor(S, m);
            Q += __shfl_xor(Q, m);
        }
        S += rx + ry;
        Q += rx * rx + ry * ry;
        float mu = S * (1.f / FDIM);
        float var = Q * (1.f / FDIM) - mu * mu;
        float w = (s < cnt) ? rsqrtf(var + LNEPS) : 0.f;  // tail quarters: 0
        a0.x += (v0.x - mu) * w; a0.y += (v0.y - mu) * w;
        a0.z += (v0.z - mu) * w; a0.w += (v0.w - mu) * w;
        a1.x += (v1.x - mu) * w; a1.y += (v1.y - mu) * w;
        a1.z += (v1.z - mu) * w; a1.w += (v1.w - mu) * w;
        a2.x += (v2.x - mu) * w; a2.y += (v2.y - mu) * w;
        a2.z += (v2.z - mu) * w; a2.w += (v2.w - mu) * w;
        a3.x += (v3.x - mu) * w; a3.y += (v3.y - mu) * w;
        a3.z += (v3.z - mu) * w; a3.w += (v3.w - mu) * w;
        arx += (rx - mu) * w;
        ary += (ry - mu) * w;
    }
    // merge the 4 quarters: butterfly over lane bits 16 and 32
#define MRG(x)              \
    x += __shfl_xor(x, 16); \
    x += __shfl_xor(x, 32);
    MRG(a0.x) MRG(a0.y) MRG(a0.z) MRG(a0.w)
    MRG(a1.x) MRG(a1.y) MRG(a1.z) MRG(a1.w)
    MRG(a2.x) MRG(a2.y) MRG(a2.z) MRG(a2.w)
    MRG(a3.x) MRG(a3.y) MRG(a3.z) MRG(a3.w)
    MRG(arx) MRG(ary)
#undef MRG

    float4 w4 = ((const float4*)nw)[lane];  // channels lane*4 = q*64+ll*4 ✓
    float4 b4 = ((const float4*)nb)[lane];
    float4 aq = (q == 0) ? a0 : (q == 1) ? a1 : (q == 2) ? a2 : a3;
    h4v h;
    h[0] = (_Float16)(aq.x * w4.x + fcnt * b4.x);
    h[1] = (_Float16)(aq.y * w4.y + fcnt * b4.y);
    h[2] = (_Float16)(aq.z * w4.z + fcnt * b4.z);
    h[3] = (_Float16)(aq.w * w4.w + fcnt * b4.w);
    *(h4v*)(Ah + (size_t)row * FP + lane * 4) = h;
    if (lane == 0) {  // LN'd rel-pos channels, fp32, for gemm rank-2 epilogue
        ws[OFF_RP + 2 * row + 0] = arx * nw[256] + fcnt * nb[256];
        ws[OFF_RP + 2 * row + 1] = ary * nw[257] + fcnt * nb[257];
    }
}

// fp16 MFMA GEMM: out[row,col] = inv[row]*(sum_k Ah[row,k]*Wh[col,k]
//                                          + rp0[row]*wc0[col] + rp1[row]*wc1[col])
// M=32768, N=512, K=256. 128x128 tile, BK=32, DOUBLE-BUFFERED LDS (T3
// minimum-2-phase: issue next tile's global_load_lds BEFORE consuming the
// current buffer; one drain+barrier per K-step). LDS 2*(8+8)=32 KB -- same
// footprint as the old single-buffered BK=64, so occupancy is unchanged.
// Swizzle for 64B rows: LDS chunk pc = ch ^ ((r>>1)&3); fragment read uses
// kq ^ ((l15>>1)&3) -> 2-way bank aliasing (free). Accumulation order over
// K is identical to the BK=64 version -> bit-identical results.
#define GM 128
#define GN 128
#define GK2 32

__global__ __launch_bounds__(256) void k_gemm(const float* __restrict__ ws,
                                              float* __restrict__ out) {
    __shared__ __align__(16) _Float16 As[2][GM * GK2];
    __shared__ __align__(16) _Float16 Bs[2][GN * GK2];
    const _Float16* Ah = (const _Float16*)(ws + OFF_ACCH);
    const _Float16* Wh = (const _Float16*)(ws + OFF_WPH);
    const float* inv = ws + OFF_INV;
    const float* rp = ws + OFF_RP;

    int t = threadIdx.x;
    int lane = t & 63;
    int wv = t >> 6;
    int wr = wv & 1, wc = wv >> 1;
    int wg = blockIdx.x;              // 1024 blocks
    int idx = wg >> 3;                // 0..127 within XCD
    int rowtile = ((wg & 7) << 5) + (idx >> 2);  // bijective over [0,256)
    int row0 = rowtile * GM;
    int col0 = (idx & 3) * GN;
    int l15 = lane & 15, kq = lane >> 4;
    int sw2 = (l15 >> 1) & 3;  // fragment-read swizzle key (64B rows)

    // staging geometry: 512 chunks of 16B per matrix per K-step; 2/thread.
    // chunk c -> LDS row r=c>>2, phys col pc=c&3; source col ch=pc^((r>>1)&3)
    int c0 = t, c1 = 256 + t;
    int r0s = c0 >> 2, r1s = c1 >> 2;
    int ch0 = (c0 & 3) ^ ((r0s >> 1) & 3);
    int ch1 = (c1 & 3) ^ ((r1s >> 1) & 3);
    int lb0 = (wv * 64) * 8;         // wave-uniform LDS half-offset, l=0
    int lb1 = (256 + wv * 64) * 8;   // l=1
    const _Float16* gA0 = Ah + (size_t)(row0 + r0s) * FP + ch0 * 8;
    const _Float16* gA1 = Ah + (size_t)(row0 + r1s) * FP + ch1 * 8;
    const _Float16* gB0 = Wh + (size_t)(col0 + r0s) * FP + ch0 * 8;
    const _Float16* gB1 = Wh + (size_t)(col0 + r1s) * FP + ch1 * 8;

#define STAGE(buf, k0)                                                        \
    do {                                                                      \
        __builtin_amdgcn_global_load_lds(                                     \
            (const __attribute__((address_space(1))) void*)(gA0 + (k0)),      \
            (__attribute__((address_space(3))) void*)(&As[buf][0] + lb0), 16, \
            0, 0);                                                            \
        __builtin_amdgcn_global_load_lds(                                     \
            (const __attribute__((address_space(1))) void*)(gA1 + (k0)),      \
            (__attribute__((address_space(3))) void*)(&As[buf][0] + lb1), 16, \
            0, 0);                                                            \
        __builtin_amdgcn_global_load_lds(                                     \
            (const __attribute__((address_space(1))) void*)(gB0 + (k0)),      \
            (__attribute__((address_space(3))) void*)(&Bs[buf][0] + lb0), 16, \
            0, 0);                                                            \
        __builtin_amdgcn_global_load_lds(                                     \
            (const __attribute__((address_space(1))) void*)(gB1 + (k0)),      \
            (__attribute__((address_space(3))) void*)(&Bs[buf][0] + lb1), 16, \
            0, 0);                                                            \
    } while (0)

    f4v acc[4][4] = {};

    STAGE(0, 0);
    __syncthreads();  // drain prologue stage

    int cur = 0;
#pragma unroll
    for (int tstep = 0; tstep < 8; ++tstep) {
        if (tstep < 7) STAGE(cur ^ 1, (tstep + 1) * GK2);  // issue-early
        h8v af[4], bf[4];
        int lc = kq ^ sw2;  // physical 16B column for this lane
#pragma unroll
        for (int i = 0; i < 4; ++i)
            af[i] = *(const h8v*)&As[cur][(wr * 64 + i * 16 + l15) * GK2 + lc * 8];
#pragma unroll
        for (int j = 0; j < 4; ++j)
            bf[j] = *(const h8v*)&Bs[cur][(wc * 64 + j * 16 + l15) * GK2 + lc * 8];
#pragma unroll
        for (int i = 0; i < 4; ++i)
#pragma unroll
            for (int j = 0; j < 4; ++j)
                acc[i][j] = __builtin_amdgcn_mfma_f32_16x16x32_f16(
                    af[i], bf[j], acc[i][j], 0, 0, 0);
        __syncthreads();  // drains next-tile stage after ~24 instrs of cover
        cur ^= 1;
    }
#undef STAGE

    float w0[4], w1[4];
#pragma unroll
    for (int j = 0; j < 4; ++j) {
        int col = col0 + wc * 64 + j * 16 + l15;
        w0[j] = ws[OFF_WC + col];
        w1[j] = ws[OFF_WC + 512 + col];
    }
#pragma unroll
    for (int i = 0; i < 4; ++i) {
#pragma unroll
        for (int r = 0; r < 4; ++r) {
            int row = row0 + wr * 64 + i * 16 + kq * 4 + r;
            float sc = inv[row];
            float r0 = rp[2 * row], r1 = rp[2 * row + 1];
#pragma unroll
            for (int j = 0; j < 4; ++j) {
                int col = col0 + wc * 64 + j * 16 + l15;
                out[OUT_FEAT_OFF + (size_t)row * OC + col] =
                    (acc[i][j][r] + r0 * w0[j] + r1 * w1[j]) * sc;
            }
        }
    }
}

extern "C" void kernel_launch(void* const* d_in, const int* in_sizes, int n_in,
                              void* d_out, int out_size, void* d_ws, size_t ws_size,
                              hipStream_t stream) {
    const float* pos = (const float*)d_in[0];
    const float* feat = (const float*)d_in[1];
    const int* asg = (const int*)d_in[2];
    const float* nw = (const float*)d_in[3];
    const float* nb = (const float*)d_in[4];
    const float* lw = (const float*)d_in[5];
    float* out = (float*)d_out;
    float* ws = (float*)d_ws;

    hipMemsetAsync(d_ws, 0, (size_t)MEMSET_FLOATS * sizeof(float), stream);
    k_prep<<<PREP_PB + PREP_WB, 256, 0, stream>>>(pos, asg, lw, ws);
    k_gather<<<NROWS / 4, 256, 0, stream>>>(feat, pos, nw, nb, ws, out);
    k_gemm<<<NROWS / GM * (OC / GN), 256, 0, stream>>>(ws, out);
}

// Round 5
// 302.465 us; speedup vs baseline: 1.0201x; 1.0201x over previous
//
#include <hip/hip_runtime.h>

#define BB 8
#define NN 16384
#define CC 256
#define KK 4096
#define FDIM 258
#define FP 256          // GEMM K: real channels 0..255; 256/257 via rank-2 epilogue
#define OC 512
#define NPTS (BB * NN)  // 131072
#define NROWS (BB * KK) // 32768
#define CAP 64          // per-cluster list capacity (Poisson(4); max ~18)
#define LNEPS 1e-5f

// output layout (floats)
#define OUT_FEAT_OFF 65536
#define OUT_MASK_OFF (65536 + 16777216)

// workspace offsets (float units)
#define OFF_MAX 0
#define OFF_ICOUNT 16
#define MEMSET_FLOATS (16 + NROWS)            // only max + icount need zeroing
#define OFF_ACCH 32784                        // fp16 region, NROWS*FP halves
#define ACC_FSLOTS (NROWS * FP / 2)           // 4,194,304
#define OFF_INV (OFF_ACCH + ACC_FSLOTS)       // 4,227,088
#define OFF_LIST (OFF_INV + NROWS)            // 4,259,856 (ints)
#define OFF_WPH (OFF_LIST + NROWS * CAP)      // 6,357,008 (fp16, OC*FP halves)
#define OFF_RP (OFF_WPH + OC * FP / 2)        // 6,422,544 (2 fp32 per row)
#define OFF_WC (OFF_RP + NROWS * 2)           // 6,488,080 (wcol 2x512 fp32)

typedef _Float16 h8v __attribute__((ext_vector_type(8)));
typedef _Float16 h4v __attribute__((ext_vector_type(4)));
typedef float f4v __attribute__((ext_vector_type(4)));

// Fused prep: blocks [0,512) -> per-point max-reduce + cluster list build;
// blocks [512,640) -> lin_w cols 0..255 into fp16 Wh[OC][FP];
// block 640 -> lin_w cols 256/257 into fp32 wc[2][OC].
#define PREP_PB 512
#define PREP_WB 129

__global__ __launch_bounds__(256) void k_prep(const float* __restrict__ pos,
                                              const int* __restrict__ asg,
                                              const float* __restrict__ lw,
                                              float* ws) {
    int bid = blockIdx.x;
    if (bid < PREP_PB) {
        int i = bid * 256 + threadIdx.x;  // exactly covers NPTS
        int* icount = (int*)(ws + OFF_ICOUNT);
        int* list = (int*)(ws + OFF_LIST);
        float2 p = ((const float2*)pos)[i];
        int b = i >> 14;
        int row = b * KK + asg[i];
        int slot = atomicAdd(icount + row, 1);
        if (slot < CAP) list[row * CAP + slot] = i;
        float mx = p.x, my = p.y;
        for (int off = 32; off > 0; off >>= 1) {
            mx = fmaxf(mx, __shfl_down(mx, off));
            my = fmaxf(my, __shfl_down(my, off));
        }
        if ((threadIdx.x & 63) == 0) {
            atomicMax((int*)(ws + OFF_MAX + 0), __float_as_int(mx));
            atomicMax((int*)(ws + OFF_MAX + 1), __float_as_int(my));
        }
    } else if (bid < PREP_PB + 128) {
        _Float16* Wh = (_Float16*)(ws + OFF_WPH);
        int e = (bid - PREP_PB) * 1024 + threadIdx.x * 4;  // 4 halves/thread
        int o = e >> 8, f = e & 255;  // f <= 252 < FDIM: no pad conditional
        h4v h;
#pragma unroll
        for (int u = 0; u < 4; ++u) h[u] = (_Float16)lw[o * FDIM + f + u];
        *(h4v*)(Wh + e) = h;
    } else {
        int o = threadIdx.x;  // cols 256/257 of lw, fp32
        ws[OFF_WC + o] = lw[o * FDIM + 256];
        ws[OFF_WC + 512 + o] = lw[o * FDIM + 257];
        o += 256;
        ws[OFF_WC + o] = lw[o * FDIM + 256];
        ws[OFF_WC + 512 + o] = lw[o * FDIM + 257];
    }
}

// One wave per cluster row, QUARTER-wave per point: 4 points in flight per
// batch (4 independent 256B-coalesced loads), 4-step shfl_xor reduce within
// each 16-lane quarter for mean/var, single xor-16/32 merge at the end.
// LN'd rel-pos channels (256/257) go to rp[row][2] for the gemm epilogue.
__global__ __launch_bounds__(256) void k_gather(
    const float* __restrict__ feat, const float* __restrict__ pos,
    const float* __restrict__ nw, const float* __restrict__ nb,
    float* ws, float* __restrict__ out) {
    int t = threadIdx.x;
    int lane = t & 63;
    int bswz = ((blockIdx.x & 7) << 10) + (blockIdx.x >> 3);  // XCD-grouped rows
    int row = (bswz << 2) + (t >> 6);  // 4 waves/block
    int q = lane >> 4;   // quarter id = point slot within batch
    int ll = lane & 15;  // lane within quarter: channels q*64 + ll*4 + j
    const int* icount = (const int*)(ws + OFF_ICOUNT);
    const int* list = (const int*)(ws + OFF_LIST);
    _Float16* Ah = (_Float16*)(ws + OFF_ACCH);

    int cnt = icount[row];
    if (cnt > CAP) cnt = CAP;
    float fcnt = (float)cnt;
    float invc = 1.f / fmaxf(fcnt, 1.f);
    float mxx = ws[OFF_MAX + 0], mxy = ws[OFF_MAX + 1];

    int ptl = (lane < cnt) ? list[row * CAP + lane] : 0;
    float px = 0.f, py = 0.f;
    if (lane < cnt) {
        float2 p = ((const float2*)pos)[ptl];
        px = p.x / mxx;
        py = p.y / mxy;
    }
    float sx = px, sy = py;
    for (int m = 32; m; m >>= 1) {
        sx += __shfl_xor(sx, m);
        sy += __shfl_xor(sy, m);
    }
    float meanx = sx * invc, meany = sy * invc;
    float valid = (cnt > 0) ? 1.f : 0.f;
    if (lane == 0) {
        out[2 * row + 0] = meanx * valid;
        out[2 * row + 1] = meany * valid;
        out[OUT_MASK_OFF + row] = valid;
        ws[OFF_INV + row] = invc;
    }

    // acc a<u>: channels u*64 + ll*4 + j, partial over points s≡q (mod 4)
    float4 a0 = {0.f, 0.f, 0.f, 0.f}, a1 = {0.f, 0.f, 0.f, 0.f};
    float4 a2 = {0.f, 0.f, 0.f, 0.f}, a3 = {0.f, 0.f, 0.f, 0.f};
    float arx = 0.f, ary = 0.f;
    for (int s0 = 0; s0 < cnt; s0 += 4) {
        int s = s0 + q;  // this quarter's point (may be >= cnt on tail)
        int pt = __shfl(ptl, s);
        float rx = __shfl(px, s) - meanx;
        float ry = __shfl(py, s) - meany;
        const float4* fr = (const float4*)(feat + (size_t)pt * CC);
        float4 v0 = fr[ll];       // channels ll*4       .. +3
        float4 v1 = fr[16 + ll];  // channels 64+ll*4    .. +3
        float4 v2 = fr[32 + ll];  // channels 128+ll*4   .. +3
        float4 v3 = fr[48 + ll];  // channels 192+ll*4   .. +3
        float S = (v0.x + v0.y + v0.z + v0.w) + (v1.x + v1.y + v1.z + v1.w) +
                  (v2.x + v2.y + v2.z + v2.w) + (v3.x + v3.y + v3.z + v3.w);
        float Q = v0.x * v0.x + v0.y * v0.y + v0.z * v0.z + v0.w * v0.w +
                  v1.x * v1.x + v1.y * v1.y + v1.z * v1.z + v1.w * v1.w +
                  v2.x * v2.x + v2.y * v2.y + v2.z * v2.z + v2.w * v2.w +
                  v3.x * v3.x + v3.y * v3.y + v3.z * v3.z + v3.w * v3.w;
        for (int m = 1; m < 16; m <<= 1) {  // reduce within quarter
            S += __shfl_xor(S, m);
            Q += __shfl_xor(Q, m);
        }
        S += rx + ry;
        Q += rx * rx + ry * ry;
        float mu = S * (1.f / FDIM);
        float var = Q * (1.f / FDIM) - mu * mu;
        float w = (s < cnt) ? rsqrtf(var + LNEPS) : 0.f;  // tail quarters: 0
        a0.x += (v0.x - mu) * w; a0.y += (v0.y - mu) * w;
        a0.z += (v0.z - mu) * w; a0.w += (v0.w - mu) * w;
        a1.x += (v1.x - mu) * w; a1.y += (v1.y - mu) * w;
        a1.z += (v1.z - mu) * w; a1.w += (v1.w - mu) * w;
        a2.x += (v2.x - mu) * w; a2.y += (v2.y - mu) * w;
        a2.z += (v2.z - mu) * w; a2.w += (v2.w - mu) * w;
        a3.x += (v3.x - mu) * w; a3.y += (v3.y - mu) * w;
        a3.z += (v3.z - mu) * w; a3.w += (v3.w - mu) * w;
        arx += (rx - mu) * w;
        ary += (ry - mu) * w;
    }
    // merge the 4 quarters: butterfly over lane bits 16 and 32
#define MRG(x)              \
    x += __shfl_xor(x, 16); \
    x += __shfl_xor(x, 32);
    MRG(a0.x) MRG(a0.y) MRG(a0.z) MRG(a0.w)
    MRG(a1.x) MRG(a1.y) MRG(a1.z) MRG(a1.w)
    MRG(a2.x) MRG(a2.y) MRG(a2.z) MRG(a2.w)
    MRG(a3.x) MRG(a3.y) MRG(a3.z) MRG(a3.w)
    MRG(arx) MRG(ary)
#undef MRG

    float4 w4 = ((const float4*)nw)[lane];  // channels lane*4 = q*64+ll*4 ✓
    float4 b4 = ((const float4*)nb)[lane];
    float4 aq = (q == 0) ? a0 : (q == 1) ? a1 : (q == 2) ? a2 : a3;
    h4v h;
    h[0] = (_Float16)(aq.x * w4.x + fcnt * b4.x);
    h[1] = (_Float16)(aq.y * w4.y + fcnt * b4.y);
    h[2] = (_Float16)(aq.z * w4.z + fcnt * b4.z);
    h[3] = (_Float16)(aq.w * w4.w + fcnt * b4.w);
    *(h4v*)(Ah + (size_t)row * FP + lane * 4) = h;
    if (lane == 0) {  // LN'd rel-pos channels, fp32, for gemm rank-2 epilogue
        ws[OFF_RP + 2 * row + 0] = arx * nw[256] + fcnt * nb[256];
        ws[OFF_RP + 2 * row + 1] = ary * nw[257] + fcnt * nb[257];
    }
}

// fp16 MFMA GEMM: out[row,col] = inv[row]*(sum_k Ah[row,k]*Wh[col,k]
//                                          + rp0[row]*wc0[col] + rp1[row]*wc1[col])
// M=32768, N=512, K=256. 128x128 tile, BK=64, 4 waves of 64x64.
// Staging via global_load_lds width=16 with PRE-SWIZZLED SOURCE chunk
// (ch = (c&7) ^ (r&7)) and linear LDS dest -> LDS image identical to the
// verified XOR-swizzled layout; fragment reads keep the same lc^sw key.
// NOTE: BK=32 double-buffer variant REGRESSED (308.6 vs 303.6): doubled
// barrier count (each with vmcnt-drain) outweighed the overlap at this
// tile size; compiler's implicit wave-level overlap already covers it.
#define GM 128
#define GN 128
#define GK 64

__global__ __launch_bounds__(256) void k_gemm(const float* __restrict__ ws,
                                              float* __restrict__ out) {
    __shared__ __align__(16) _Float16 As[GM * GK];
    __shared__ __align__(16) _Float16 Bs[GN * GK];
    const _Float16* Ah = (const _Float16*)(ws + OFF_ACCH);
    const _Float16* Wh = (const _Float16*)(ws + OFF_WPH);
    const float* inv = ws + OFF_INV;
    const float* rp = ws + OFF_RP;

    int t = threadIdx.x;
    int lane = t & 63;
    int wv = t >> 6;
    int wr = wv & 1, wc = wv >> 1;
    int wg = blockIdx.x;              // 1024 blocks
    int idx = wg >> 3;                // 0..127 within XCD
    int rowtile = ((wg & 7) << 5) + (idx >> 2);  // bijective over [0,256)
    int row0 = rowtile * GM;
    int col0 = (idx & 3) * GN;
    int l15 = lane & 15, kq = lane >> 4;
    int sw = l15 & 7;  // fragment-read swizzle key

    f4v acc[4][4] = {};

    for (int k0 = 0; k0 < FP; k0 += GK) {
#pragma unroll
        for (int l = 0; l < 4; ++l) {
            int c = l * 256 + t;          // 16B-chunk id, 1024 per matrix
            int r = c >> 3;               // tile row (8 chunks per row)
            int ch = (c & 7) ^ (r & 7);   // pre-swizzled source chunk
            int lb = (l * 256 + wv * 64) * 8;  // wave-uniform LDS base (halves)
            __builtin_amdgcn_global_load_lds(
                (const __attribute__((address_space(1))) void*)(
                    Ah + (size_t)(row0 + r) * FP + k0 + ch * 8),
                (__attribute__((address_space(3))) void*)(As + lb), 16, 0, 0);
            __builtin_amdgcn_global_load_lds(
                (const __attribute__((address_space(1))) void*)(
                    Wh + (size_t)(col0 + r) * FP + k0 + ch * 8),
                (__attribute__((address_space(3))) void*)(Bs + lb), 16, 0, 0);
        }
        __syncthreads();  // compiler drains vmcnt(0) before s_barrier
#pragma unroll
        for (int ks = 0; ks < 2; ++ks) {
            h8v af[4], bf[4];
            int lc = ((ks << 2) | kq);
#pragma unroll
            for (int i = 0; i < 4; ++i)
                af[i] = *(const h8v*)&As[(wr * 64 + i * 16 + l15) * GK + ((lc ^ sw) * 8)];
#pragma unroll
            for (int j = 0; j < 4; ++j)
                bf[j] = *(const h8v*)&Bs[(wc * 64 + j * 16 + l15) * GK + ((lc ^ sw) * 8)];
#pragma unroll
            for (int i = 0; i < 4; ++i)
#pragma unroll
                for (int j = 0; j < 4; ++j)
                    acc[i][j] = __builtin_amdgcn_mfma_f32_16x16x32_f16(
                        af[i], bf[j], acc[i][j], 0, 0, 0);
        }
        __syncthreads();
    }

    float w0[4], w1[4];
#pragma unroll
    for (int j = 0; j < 4; ++j) {
        int col = col0 + wc * 64 + j * 16 + l15;
        w0[j] = ws[OFF_WC + col];
        w1[j] = ws[OFF_WC + 512 + col];
    }
#pragma unroll
    for (int i = 0; i < 4; ++i) {
#pragma unroll
        for (int r = 0; r < 4; ++r) {
            int row = row0 + wr * 64 + i * 16 + kq * 4 + r;
            float sc = inv[row];
            float r0 = rp[2 * row], r1 = rp[2 * row + 1];
#pragma unroll
            for (int j = 0; j < 4; ++j) {
                int col = col0 + wc * 64 + j * 16 + l15;
                out[OUT_FEAT_OFF + (size_t)row * OC + col] =
                    (acc[i][j][r] + r0 * w0[j] + r1 * w1[j]) * sc;
            }
        }
    }
}

extern "C" void kernel_launch(void* const* d_in, const int* in_sizes, int n_in,
                              void* d_out, int out_size, void* d_ws, size_t ws_size,
                              hipStream_t stream) {
    const float* pos = (const float*)d_in[0];
    const float* feat = (const float*)d_in[1];
    const int* asg = (const int*)d_in[2];
    const float* nw = (const float*)d_in[3];
    const float* nb = (const float*)d_in[4];
    const float* lw = (const float*)d_in[5];
    float* out = (float*)d_out;
    float* ws = (float*)d_ws;

    hipMemsetAsync(d_ws, 0, (size_t)MEMSET_FLOATS * sizeof(float), stream);
    k_prep<<<PREP_PB + PREP_WB, 256, 0, stream>>>(pos, asg, lw, ws);
    k_gather<<<NROWS / 4, 256, 0, stream>>>(feat, pos, nw, nb, ws, out);
    k_gemm<<<NROWS / GM * (OC / GN), 256, 0, stream>>>(ws, out);
}